// Round 1
// baseline (726.106 us; speedup 1.0000x reference)
//
#include <hip/hip_runtime.h>

#define NUM_FIELDS 10
#define VOCAB 100000
#define EMBED_DIM 16
#define BATCH 16384
#define NPAIRS 45

// Packed (i | j<<8) for the 45 upper-triangle pairs, row-major (triu k=1 order).
__device__ __constant__ unsigned short PAIR_IJ[NPAIRS] = {
    // i=0, j=1..9
    0x0100, 0x0200, 0x0300, 0x0400, 0x0500, 0x0600, 0x0700, 0x0800, 0x0900,
    // i=1, j=2..9
    0x0201, 0x0301, 0x0401, 0x0501, 0x0601, 0x0701, 0x0801, 0x0901,
    // i=2, j=3..9
    0x0302, 0x0402, 0x0502, 0x0602, 0x0702, 0x0802, 0x0902,
    // i=3, j=4..9
    0x0403, 0x0503, 0x0603, 0x0703, 0x0803, 0x0903,
    // i=4, j=5..9
    0x0504, 0x0604, 0x0704, 0x0804, 0x0904,
    // i=5, j=6..9
    0x0605, 0x0705, 0x0805, 0x0905,
    // i=6, j=7..9
    0x0706, 0x0806, 0x0906,
    // i=7, j=8..9
    0x0807, 0x0907,
    // i=8, j=9
    0x0908
};

// One thread per output float4: tid = ((b*45)+p)*4 + d4.
// 4 consecutive lanes (d4=0..3) read one contiguous 64B emb row -> single
// coalesced transaction; writes are flat-ordered -> fully coalesced.
__global__ __launch_bounds__(256) void ffm_pair_kernel(
        const int* __restrict__ x,
        const float* __restrict__ emb,
        float* __restrict__ out) {
    const int tid = blockIdx.x * blockDim.x + threadIdx.x;
    const int total = BATCH * NPAIRS * 4;
    if (tid >= total) return;

    const int d4 = tid & 3;
    const int bp = tid >> 2;          // b*45 + p
    const int p  = bp % NPAIRS;
    const int b  = bp / NPAIRS;

    const unsigned int ij = PAIR_IJ[p];
    const int i = (int)(ij & 0xff);
    const int j = (int)(ij >> 8);

    // xo[b,f] = x[b,f] + f*VOCAB  (global row within a 1M-row table)
    const int xi = x[b * NUM_FIELDS + i] + i * VOCAB;
    const int xj = x[b * NUM_FIELDS + j] + j * VOCAB;

    // emb is (NUM_FIELDS, NUM_FIELDS*VOCAB, EMBED_DIM) fp32
    const size_t rowA = ((size_t)j * (NUM_FIELDS * VOCAB) + (size_t)xi) * EMBED_DIM;
    const size_t rowB = ((size_t)i * (NUM_FIELDS * VOCAB) + (size_t)xj) * EMBED_DIM;

    const float4 a = *(const float4*)(emb + rowA + (size_t)d4 * 4);
    const float4 c = *(const float4*)(emb + rowB + (size_t)d4 * 4);

    float4 r;
    r.x = a.x * c.x;
    r.y = a.y * c.y;
    r.z = a.z * c.z;
    r.w = a.w * c.w;

    ((float4*)out)[tid] = r;
}

extern "C" void kernel_launch(void* const* d_in, const int* in_sizes, int n_in,
                              void* d_out, int out_size, void* d_ws, size_t ws_size,
                              hipStream_t stream) {
    const int*   x   = (const int*)d_in[0];
    const float* emb = (const float*)d_in[1];
    float*       out = (float*)d_out;

    const int total   = BATCH * NPAIRS * 4;   // 2,949,120 threads (one per float4)
    const int block   = 256;
    const int grid    = (total + block - 1) / block;  // 11520 blocks

    ffm_pair_kernel<<<grid, block, 0, stream>>>(x, emb, out);
}

// Round 3
// 714.534 us; speedup vs baseline: 1.0162x; 1.0162x over previous
//
#include <hip/hip_runtime.h>

#define NUM_FIELDS 10
#define VOCAB 100000
#define EMBED_DIM 16
#define BATCH 16384
#define NPAIRS 45
#define ITEMS_PER_THREAD 4

// Native Clang vector type — accepted by __builtin_nontemporal_load/store
// (HIP_vector_type float4 is a struct and is rejected).
typedef float v4f __attribute__((ext_vector_type(4)));

// Packed (i | j<<8) for the 45 upper-triangle pairs, row-major (triu k=1 order).
__device__ __constant__ unsigned short PAIR_IJ[NPAIRS] = {
    0x0100, 0x0200, 0x0300, 0x0400, 0x0500, 0x0600, 0x0700, 0x0800, 0x0900,
    0x0201, 0x0301, 0x0401, 0x0501, 0x0601, 0x0701, 0x0801, 0x0901,
    0x0302, 0x0402, 0x0502, 0x0602, 0x0702, 0x0802, 0x0902,
    0x0403, 0x0503, 0x0603, 0x0703, 0x0803, 0x0903,
    0x0504, 0x0604, 0x0704, 0x0804, 0x0904,
    0x0605, 0x0705, 0x0805, 0x0905,
    0x0706, 0x0806, 0x0906,
    0x0807, 0x0907,
    0x0908
};

// One item = one output float4: item = ((b*45)+p)*4 + d4.
// 4 consecutive lanes (d4=0..3) read one contiguous 64B emb row -> single
// coalesced transaction; writes are flat-ordered -> fully coalesced.
// Each thread processes ITEMS_PER_THREAD items spaced total/IPT apart so
// every item-slice keeps perfect coalescing; all 2*IPT gather loads are
// issued before any use to maximize outstanding VMEM requests per wave.
__global__ __launch_bounds__(256) void ffm_pair_kernel(
        const int* __restrict__ x,
        const float* __restrict__ emb,
        float* __restrict__ out) {
    const int total  = BATCH * NPAIRS * 4;           // 2,949,120
    const int stride = total / ITEMS_PER_THREAD;     //   737,280
    const int tid0   = blockIdx.x * blockDim.x + threadIdx.x;
    if (tid0 >= stride) return;

    v4f a[ITEMS_PER_THREAD];
    v4f c[ITEMS_PER_THREAD];

    // Phase 1: compute addresses and issue ALL gather loads.
    #pragma unroll
    for (int k = 0; k < ITEMS_PER_THREAD; ++k) {
        const int tid = tid0 + k * stride;
        const int d4 = tid & 3;
        const int bp = tid >> 2;          // b*45 + p
        const int p  = bp % NPAIRS;
        const int b  = bp / NPAIRS;

        const unsigned int ij = PAIR_IJ[p];
        const int i = (int)(ij & 0xff);
        const int j = (int)(ij >> 8);

        const int xi = x[b * NUM_FIELDS + i] + i * VOCAB;
        const int xj = x[b * NUM_FIELDS + j] + j * VOCAB;

        const size_t rowA = ((size_t)j * (NUM_FIELDS * VOCAB) + (size_t)xi) * EMBED_DIM;
        const size_t rowB = ((size_t)i * (NUM_FIELDS * VOCAB) + (size_t)xj) * EMBED_DIM;

        a[k] = __builtin_nontemporal_load((const v4f*)(emb + rowA + (size_t)d4 * 4));
        c[k] = __builtin_nontemporal_load((const v4f*)(emb + rowB + (size_t)d4 * 4));
    }

    // Phase 2: multiply and store (streaming, nontemporal).
    #pragma unroll
    for (int k = 0; k < ITEMS_PER_THREAD; ++k) {
        const int tid = tid0 + k * stride;
        const v4f r = a[k] * c[k];
        __builtin_nontemporal_store(r, (v4f*)out + tid);
    }
}

extern "C" void kernel_launch(void* const* d_in, const int* in_sizes, int n_in,
                              void* d_out, int out_size, void* d_ws, size_t ws_size,
                              hipStream_t stream) {
    const int*   x   = (const int*)d_in[0];
    const float* emb = (const float*)d_in[1];
    float*       out = (float*)d_out;

    const int total  = BATCH * NPAIRS * 4;
    const int nthr   = total / ITEMS_PER_THREAD;     // 737,280
    const int block  = 256;
    const int grid   = (nthr + block - 1) / block;   // 2,880 blocks

    ffm_pair_kernel<<<grid, block, 0, stream>>>(x, emb, out);
}